// Round 1
// baseline (176.430 us; speedup 1.0000x reference)
//
#include <hip/hip_runtime.h>
#include <math.h>

#define B_N     16384
#define D_N     512
#define NPAIR   (B_N/2)
#define NBUCKET 16384

__device__ __forceinline__ float wave_reduce(float v) {
    #pragma unroll
    for (int m = 32; m >= 1; m >>= 1) v += __shfl_xor(v, m, 64);
    return v;
}

__device__ __forceinline__ int bucket_of(float t) {
    // exact: multiply by 2^14, floor; monotonic in t
    int b = (int)(t * 16384.0f);
    return min(max(b, 0), NBUCKET - 1);
}

__device__ __forceinline__ float dot4(float4 a, float4 b) {
    return a.x*b.x + a.y*b.y + a.z*b.z + a.w*b.w;
}

// acc layout: [0]=con_sum [1]=nll_sum [2]=evs_sum [3]=cox_sum
__global__ void k_stats(const float* __restrict__ hazard,
                        const float* __restrict__ score,
                        const float* __restrict__ time,
                        const int*   __restrict__ event,
                        int* __restrict__ counts, float* __restrict__ sumE,
                        float* __restrict__ acc)
{
    int i = blockIdx.x * blockDim.x + threadIdx.x;
    float nll_p = 0.f, ev_p = 0.f;
    if (i < B_N) {
        float t = time[i];
        int b = bucket_of(t);
        float e = __expf(hazard[i]);
        atomicAdd(&counts[b], 1);
        atomicAdd(&sumE[b], e);
        int ev = event[i];
        nll_p = score[i * 2 + ev];
        ev_p  = (float)ev;
    }
    nll_p = wave_reduce(nll_p);
    ev_p  = wave_reduce(ev_p);
    if ((threadIdx.x & 63) == 0) {
        atomicAdd(&acc[1], nll_p);
        atomicAdd(&acc[2], ev_p);
    }
}

// 1 block x 1024 threads: pos = exclusive prefix of counts;
// cumH[b] = sum of sumE over buckets strictly greater than b.
__global__ __launch_bounds__(1024) void k_scan(const int* __restrict__ counts,
                                               const float* __restrict__ sumE,
                                               int* __restrict__ pos,
                                               float* __restrict__ cumH)
{
    __shared__ int   lsi[1024];
    __shared__ float lsf[1024];
    const int tid = threadIdx.x;
    const int base = tid * 16;

    int c[16]; int s = 0;
    #pragma unroll
    for (int k = 0; k < 16; ++k) c[k] = counts[base + k];
    #pragma unroll
    for (int k = 0; k < 16; ++k) { int t = c[k]; c[k] = s; s += t; }
    lsi[tid] = s;
    __syncthreads();
    for (int d = 1; d < 1024; d <<= 1) {
        int v = (tid >= d) ? lsi[tid - d] : 0;
        __syncthreads();
        lsi[tid] += v;
        __syncthreads();
    }
    int ebase = lsi[tid] - s;
    #pragma unroll
    for (int k = 0; k < 16; ++k) pos[base + k] = ebase + c[k];

    float f[16]; float fs = 0.f;
    #pragma unroll
    for (int k = 0; k < 16; ++k) { f[k] = sumE[base + k]; fs += f[k]; }
    lsf[tid] = fs;
    __syncthreads();
    for (int d = 1; d < 1024; d <<= 1) {
        float v = (tid >= d) ? lsf[tid - d] : 0.f;
        __syncthreads();
        lsf[tid] += v;
        __syncthreads();
    }
    float total = lsf[1023];
    float running = total - lsf[tid];   // sum of chunks after this one
    #pragma unroll
    for (int k = 15; k >= 0; --k) { cumH[base + k] = running; running += f[k]; }
}

__global__ void k_scatter(const float* __restrict__ hazard,
                          const float* __restrict__ time,
                          const int* __restrict__ pos, int* __restrict__ cursor,
                          float* __restrict__ st, float* __restrict__ se,
                          int* __restrict__ sidx)
{
    int i = blockIdx.x * blockDim.x + threadIdx.x;
    if (i < B_N) {
        float t = time[i];
        int b = bucket_of(t);
        int p = pos[b] + atomicAdd(&cursor[b], 1);
        st[p] = t;
        se[p] = __expf(hazard[i]);
        sidx[p] = i;
    }
}

__global__ void k_cox(const float* __restrict__ hazard,
                      const float* __restrict__ time,
                      const int* __restrict__ event,
                      const int* __restrict__ pos, const int* __restrict__ counts,
                      const float* __restrict__ cumH,
                      const float* __restrict__ st, const float* __restrict__ se,
                      const int* __restrict__ sidx, float* __restrict__ acc)
{
    int i = blockIdx.x * blockDim.x + threadIdx.x;
    float local = 0.f;
    if (i < B_N && event[i] == 1) {
        float t = time[i];
        int b = bucket_of(t);
        float cum = cumH[b];
        int s0 = pos[b], cnt = counts[b];
        for (int q = s0; q < s0 + cnt; ++q) {
            float tq = st[q];
            // stable argsort(-time): j before-or-equal i iff t_j > t_i, or tie and j <= i
            if (tq > t || (tq == t && sidx[q] <= i)) cum += se[q];
        }
        local = hazard[i] - logf(cum + 1e-6f);
    }
    local = wave_reduce(local);
    if ((threadIdx.x & 63) == 0) atomicAdd(&acc[3], local);
}

__global__ __launch_bounds__(256) void k_con(const float* __restrict__ rep1,
                                             const float* __restrict__ rep2,
                                             const float* __restrict__ rep3,
                                             const int* __restrict__ x1_idx,
                                             const int* __restrict__ x2_idx,
                                             float* __restrict__ acc)
{
    __shared__ float wsum[4];
    const int lane = threadIdx.x & 63;
    const int wave = threadIdx.x >> 6;
    const int p = blockIdx.x * 4 + wave;   // grid = 2048 blocks -> p in [0, 8192)
    const int ia = x1_idx[p];
    const int ib = x2_idx[p];
    const float4* A1 = (const float4*)(rep1 + (size_t)ia * D_N);
    const float4* A2 = (const float4*)(rep2 + (size_t)ia * D_N);
    const float4* A3 = (const float4*)(rep3 + (size_t)ia * D_N);
    const float4* B1 = (const float4*)(rep1 + (size_t)ib * D_N);
    const float4* B2 = (const float4*)(rep2 + (size_t)ib * D_N);
    const float4* B3 = (const float4*)(rep3 + (size_t)ib * D_N);

    float v[15];
    #pragma unroll
    for (int k = 0; k < 15; ++k) v[k] = 0.f;

    #pragma unroll
    for (int r = 0; r < 2; ++r) {
        const int k = lane + r * 64;       // 128 float4 per row
        float4 a1 = A1[k], a2 = A2[k], a3 = A3[k];
        float4 b1 = B1[k], b2 = B2[k], b3 = B3[k];
        v[0]  += dot4(a1, a1); v[1]  += dot4(a2, a2); v[2]  += dot4(a3, a3);
        v[3]  += dot4(b1, b1); v[4]  += dot4(b2, b2); v[5]  += dot4(b3, b3);
        v[6]  += dot4(a1, a2); v[7]  += dot4(a1, a3); v[8]  += dot4(a2, a3);
        v[9]  += dot4(b1, b2); v[10] += dot4(b1, b3); v[11] += dot4(b2, b3);
        v[12] += dot4(a1, b1); v[13] += dot4(a2, b2); v[14] += dot4(a3, b3);
    }
    #pragma unroll
    for (int k = 0; k < 15; ++k) v[k] = wave_reduce(v[k]);

    if (lane == 0) {
        float n1a = fmaxf(sqrtf(v[0]), 1e-8f), n2a = fmaxf(sqrtf(v[1]), 1e-8f), n3a = fmaxf(sqrtf(v[2]), 1e-8f);
        float n1b = fmaxf(sqrtf(v[3]), 1e-8f), n2b = fmaxf(sqrtf(v[4]), 1e-8f), n3b = fmaxf(sqrtf(v[5]), 1e-8f);
        float dxx = v[6]/(n1a*n2a) + v[7]/(n1a*n3a) + v[8]/(n2a*n3a);
        float dyy = v[9]/(n1b*n2b) + v[10]/(n1b*n3b) + v[11]/(n2b*n3b);
        float dxy = v[12]/(n1a*n1b) + v[13]/(n2a*n2b) + v[14]/(n3a*n3b);
        float s = 0.2f + dxy - 0.5f*dxx - 0.5f*dyy;
        wsum[wave] = log1pf(expf(s));
    }
    __syncthreads();
    if (threadIdx.x == 0) {
        float t = wsum[0] + wsum[1] + wsum[2] + wsum[3];
        atomicAdd(&acc[0], t);
    }
}

__global__ void k_final(const float* __restrict__ acc, float* __restrict__ out)
{
    if (threadIdx.x == 0 && blockIdx.x == 0) {
        float con = acc[0] / (float)NPAIR;
        float nll = -acc[1] / (float)B_N;
        float evs = acc[2];
        float cox = -acc[3] / (evs + 1e-6f);
        out[0] = nll + cox + 0.3f * con;
    }
}

extern "C" void kernel_launch(void* const* d_in, const int* in_sizes, int n_in,
                              void* d_out, int out_size, void* d_ws, size_t ws_size,
                              hipStream_t stream)
{
    const float* rep1   = (const float*)d_in[0];
    const float* rep2   = (const float*)d_in[1];
    const float* rep3   = (const float*)d_in[2];
    const float* hazard = (const float*)d_in[3];
    const float* score  = (const float*)d_in[4];
    const float* time_  = (const float*)d_in[5];
    const int*   event  = (const int*)d_in[6];
    const int*   x1     = (const int*)d_in[7];
    const int*   x2     = (const int*)d_in[8];
    float* out = (float*)d_out;

    char* w = (char*)d_ws;
    int*   counts = (int*)  (w + 0 * NBUCKET * 4);
    float* sumE   = (float*)(w + 1 * NBUCKET * 4);
    int*   cursor = (int*)  (w + 2 * NBUCKET * 4);
    float* acc    = (float*)(w + 3 * NBUCKET * 4);          // 16 floats
    int*   pos    = (int*)  (w + 3 * NBUCKET * 4 + 64);
    float* cumH   = (float*)(w + 4 * NBUCKET * 4 + 64);
    float* st     = (float*)(w + 5 * NBUCKET * 4 + 64);
    float* se     = (float*)(w + 6 * NBUCKET * 4 + 64);
    int*   sidx   = (int*)  (w + 7 * NBUCKET * 4 + 64);

    // zero: counts, sumE, cursor, acc (contiguous prefix)
    hipMemsetAsync(d_ws, 0, 3 * NBUCKET * 4 + 64, stream);

    k_stats  <<<B_N / 256, 256, 0, stream>>>(hazard, score, time_, event, counts, sumE, acc);
    k_scan   <<<1, 1024, 0, stream>>>(counts, sumE, pos, cumH);
    k_scatter<<<B_N / 256, 256, 0, stream>>>(hazard, time_, pos, cursor, st, se, sidx);
    k_cox    <<<B_N / 256, 256, 0, stream>>>(hazard, time_, event, pos, counts, cumH, st, se, sidx, acc);
    k_con    <<<NPAIR / 4, 256, 0, stream>>>(rep1, rep2, rep3, x1, x2, acc);
    k_final  <<<1, 64, 0, stream>>>(acc, out);
}